// Round 3
// baseline (404.312 us; speedup 1.0000x reference)
//
#include <hip/hip_runtime.h>
#include <hip/hip_cooperative_groups.h>
#include <cstdint>
#include <cstddef>

namespace cg = cooperative_groups;

#define NC   4096   // row length
#define NTHR 256
#define MAXBLK 1024

static __device__ __forceinline__ float waveReduceMax(float v) {
    #pragma unroll
    for (int off = 32; off > 0; off >>= 1)
        v = fmaxf(v, __shfl_down(v, off, 64));
    return v;
}
static __device__ __forceinline__ float waveReduceSum(float v) {
    #pragma unroll
    for (int off = 32; off > 0; off >>= 1)
        v += __shfl_down(v, off, 64);
    return v;
}

__device__ __forceinline__ float blockMax(float v, float* sred, int tid) {
    v = waveReduceMax(v);
    int lane = tid & 63, wid = tid >> 6;
    if (lane == 0) sred[wid] = v;
    __syncthreads();
    return fmaxf(fmaxf(sred[0], sred[1]), fmaxf(sred[2], sred[3]));
}

__device__ __forceinline__ void rowStatCompute(float Ex, float Ex2,
                                               float* mu_o, float* inv_o) {
    float mu  = Ex * (1.f / NC);
    float var = __fsub_rn(Ex2 * (1.f / NC), __fmul_rn(mu, mu));
    float var_f = fminf(fmaxf(rintf(var), 1.f), 65535.f);
    int vi = (int)var_f;
    int msb = min(31 - __clz(vi), 15);
    const float lut[16] = {65535.f, 46341.f, 32768.f, 23170.f, 16384.f, 11585.f,
                           8192.f, 5793.f, 4096.f, 2896.f, 2048.f, 1448.f,
                           1024.f, 724.f, 512.f, 362.f};
    *mu_o  = mu;
    *inv_o = lut[msb] * (1.f / 65536.f);
}

// ---------------- fused persistent cooperative kernel ----------------
__global__ __launch_bounds__(NTHR, 4) void k_fused(
    const float* __restrict__ x,
    const float* __restrict__ gamma,
    const float* __restrict__ beta,
    float* __restrict__ out,
    float* __restrict__ partA,      // [gridDim.x] absmax-x partials
    float* __restrict__ partY,      // [gridDim.x] absmax-y partials
    float2* __restrict__ row_stats, // [rows]
    int* __restrict__ xi8,          // packed int8, NC/4 dwords per row
    int rows, int n4)
{
    cg::grid_group grid = cg::this_grid();
    const int tid = threadIdx.x;
    const int bid = blockIdx.x;
    const int nb  = gridDim.x;
    __shared__ float sred[8];
    __shared__ float sbc[2];
    const int lane = tid & 63, wid = tid >> 6;

    // ---- Phase A: global absmax(x) -> per-block partial
    const float4* x4 = (const float4*)x;
    float m = 0.f;
    for (int i = bid * NTHR + tid; i < n4; i += nb * NTHR) {
        float4 v = x4[i];
        m = fmaxf(fmaxf(fabsf(v.x), fabsf(v.y)),
                  fmaxf(fmaxf(fabsf(v.z), fabsf(v.w)), m));
    }
    float bm = blockMax(m, sred, tid);
    if (tid == 0) partA[bid] = bm;
    grid.sync();

    // every block reduces all partials (max: order-independent, exact)
    float pm = 0.f;
    for (int i = tid; i < nb; i += NTHR) pm = fmaxf(pm, partA[i]);
    pm = blockMax(pm, sred, tid);
    __syncthreads();
    if (tid == 0) sbc[0] = pm * (1.f / 127.f);
    __syncthreads();
    const float scale_in = sbc[0];
    const float r_in = 1.f / scale_in;

    // ---- Phase B: per-row stats + int8 staging + running |y| max
    const float4* g4 = (const float4*)gamma;
    const float4* b4 = (const float4*)beta;
    float ym = 0.f;
    for (int row = bid; row < rows; row += nb) {
        const float4* xr = (const float4*)(x + (size_t)row * NC);
        int pack[4];
        float ex = 0.f, ex2 = 0.f;
        #pragma unroll
        for (int k = 0; k < 4; ++k) {
            float4 v = xr[tid + k * NTHR];
            const float* pv = (const float*)&v;
            int pk = 0;
            #pragma unroll
            for (int j = 0; j < 4; ++j) {
                float xi = fminf(fmaxf(rintf(pv[j] * r_in), -127.f), 127.f);
                int ii = (int)xi;
                pk |= (ii & 255) << (8 * j);
                float q = xi * scale_in;
                ex += q;
                float aq = fabsf(q);
                bool hi = aq >= 64.f;                      // floor(aq/64) >= 1
                int idx = hi ? min((int)(aq * 0.0625f), 15)
                             : (((int)(aq * 0.5f)) & 15);
                float sq = (float)(idx * idx);
                ex2 += hi ? sq * 256.f : sq * 16.f;        // sq_decomp * 2^(2*ALPHA)
            }
            pack[k] = pk;
        }
        int* wr = xi8 + (size_t)row * (NC / 4);
        #pragma unroll
        for (int k = 0; k < 4; ++k) wr[tid + k * NTHR] = pack[k];

        ex  = waveReduceSum(ex);
        ex2 = waveReduceSum(ex2);
        if (lane == 0) { sred[wid] = ex; sred[4 + wid] = ex2; }
        __syncthreads();
        if (tid == 0) {
            float Ex  = (sred[0] + sred[1]) + (sred[2] + sred[3]);
            float Ex2 = (sred[4] + sred[5]) + (sred[6] + sred[7]);
            float mu, inv;
            rowStatCompute(Ex, Ex2, &mu, &inv);
            row_stats[row] = make_float2(mu, inv);
            sbc[0] = mu; sbc[1] = inv;
        }
        __syncthreads();
        const float mu = sbc[0], inv = sbc[1];
        #pragma unroll
        for (int k = 0; k < 4; ++k) {
            float4 g = g4[tid + k * NTHR];
            float4 b = b4[tid + k * NTHR];
            const float* pg = (const float*)&g;
            const float* pb = (const float*)&b;
            int pk = pack[k];
            #pragma unroll
            for (int j = 0; j < 4; ++j) {
                int ii = (pk << (24 - 8 * j)) >> 24;       // sign-extend byte j
                float q = (float)ii * scale_in;
                float y = (q - mu) * inv * pg[j] + pb[j];
                ym = fmaxf(ym, fabsf(y));
            }
        }
        __syncthreads();   // protect sred/sbc reuse next row
    }
    float bym = blockMax(ym, sred, tid);
    if (tid == 0) partY[bid] = bym;
    grid.sync();

    float py = 0.f;
    for (int i = tid; i < nb; i += NTHR) py = fmaxf(py, partY[i]);
    py = blockMax(py, sred, tid);
    __syncthreads();
    if (tid == 0) sbc[0] = py * (1.f / 127.f);
    __syncthreads();
    const float scale_out = sbc[0];
    const float r_out = 1.f / scale_out;

    // ---- Phase C: finalize from staged int8
    for (int row = bid; row < rows; row += nb) {
        const float2 st = row_stats[row];
        const float mu = st.x, inv = st.y;
        const int* rd = xi8 + (size_t)row * (NC / 4);
        float4* outr = (float4*)(out + (size_t)row * NC);
        #pragma unroll
        for (int k = 0; k < 4; ++k) {
            int pk = rd[tid + k * NTHR];
            float4 g = g4[tid + k * NTHR];
            float4 b = b4[tid + k * NTHR];
            float4 o;
            const float* pg = (const float*)&g;
            const float* pb = (const float*)&b;
            float* po = (float*)&o;
            #pragma unroll
            for (int j = 0; j < 4; ++j) {
                int ii = (pk << (24 - 8 * j)) >> 24;
                float q = (float)ii * scale_in;
                float y = (q - mu) * inv * pg[j] + pb[j];
                float yi = fminf(fmaxf(rintf(y * r_out), -127.f), 127.f);
                po[j] = yi * scale_out;
            }
            outr[tid + k * NTHR] = o;
        }
    }
}

// ---------------- fallback path (non-cooperative), round-2 proven ----------------
__global__ __launch_bounds__(256) void k_absmax(const float* __restrict__ x,
                                                unsigned int* __restrict__ amax_bits,
                                                int n4) {
    int tid = blockIdx.x * blockDim.x + threadIdx.x;
    int stride = gridDim.x * blockDim.x;
    const float4* x4 = (const float4*)x;
    float m = 0.f;
    for (int i = tid; i < n4; i += stride) {
        float4 v = x4[i];
        m = fmaxf(m, fmaxf(fmaxf(fabsf(v.x), fabsf(v.y)),
                           fmaxf(fabsf(v.z), fabsf(v.w))));
    }
    __shared__ float sred[8];
    float b = blockMax(m, sred, threadIdx.x);
    if (threadIdx.x == 0) atomicMax(amax_bits, __float_as_uint(b));
}

__global__ __launch_bounds__(256) void k_rowstats(
    const float* __restrict__ x, const float* __restrict__ gamma,
    const float* __restrict__ beta, const unsigned int* __restrict__ amax_x_bits,
    unsigned int* __restrict__ amax_y_bits, float2* __restrict__ row_stats,
    int* __restrict__ xi8)
{
    const int row = blockIdx.x;
    const float scale_in = __uint_as_float(*amax_x_bits) * (1.0f / 127.0f);
    const float r_in = 1.0f / scale_in;
    const float4* xr = (const float4*)(x + (size_t)row * NC);
    const float4* g4 = (const float4*)gamma;
    const float4* b4 = (const float4*)beta;
    int pack[4];
    float ex = 0.f, ex2 = 0.f;
    #pragma unroll
    for (int k = 0; k < 4; ++k) {
        float4 v = xr[threadIdx.x + k * 256];
        const float* pv = (const float*)&v;
        int pk = 0;
        #pragma unroll
        for (int j = 0; j < 4; ++j) {
            float xi = fminf(fmaxf(rintf(pv[j] * r_in), -127.f), 127.f);
            int ii = (int)xi;
            pk |= (ii & 255) << (8 * j);
            float q = xi * scale_in;
            ex += q;
            float aq = fabsf(q);
            bool hi = aq >= 64.f;
            int idx = hi ? min((int)(aq * 0.0625f), 15) : (((int)(aq * 0.5f)) & 15);
            float sq = (float)(idx * idx);
            ex2 += hi ? sq * 256.f : sq * 16.f;
        }
        pack[k] = pk;
    }
    int* wr = xi8 + (size_t)row * (NC / 4);
    #pragma unroll
    for (int k = 0; k < 4; ++k) wr[threadIdx.x + k * 256] = pack[k];
    ex  = waveReduceSum(ex);
    ex2 = waveReduceSum(ex2);
    __shared__ float sred[8];
    __shared__ float sbc[2];
    int lane = threadIdx.x & 63, wid = threadIdx.x >> 6;
    if (lane == 0) { sred[wid] = ex; sred[4 + wid] = ex2; }
    __syncthreads();
    if (threadIdx.x == 0) {
        float Ex  = (sred[0] + sred[1]) + (sred[2] + sred[3]);
        float Ex2 = (sred[4] + sred[5]) + (sred[6] + sred[7]);
        float mu, inv;
        rowStatCompute(Ex, Ex2, &mu, &inv);
        sbc[0] = mu; sbc[1] = inv;
        row_stats[row] = make_float2(mu, inv);
    }
    __syncthreads();
    const float mu = sbc[0], inv = sbc[1];
    float ym = 0.f;
    #pragma unroll
    for (int k = 0; k < 4; ++k) {
        float4 g = g4[threadIdx.x + k * 256];
        float4 b = b4[threadIdx.x + k * 256];
        const float* pg = (const float*)&g;
        const float* pb = (const float*)&b;
        int pk = pack[k];
        #pragma unroll
        for (int j = 0; j < 4; ++j) {
            int ii = (pk << (24 - 8 * j)) >> 24;
            float q = (float)ii * scale_in;
            float y = (q - mu) * inv * pg[j] + pb[j];
            ym = fmaxf(ym, fabsf(y));
        }
    }
    __syncthreads();
    float b = blockMax(ym, sred, threadIdx.x);
    if (threadIdx.x == 0) atomicMax(amax_y_bits, __float_as_uint(b));
}

__global__ __launch_bounds__(256) void k_finalize_i8(
    const int* __restrict__ xi8, const float* __restrict__ gamma,
    const float* __restrict__ beta, const unsigned int* __restrict__ amax_x_bits,
    const unsigned int* __restrict__ amax_y_bits,
    const float2* __restrict__ row_stats, float* __restrict__ out)
{
    const int row = blockIdx.x;
    const float scale_in  = __uint_as_float(*amax_x_bits) * (1.0f / 127.0f);
    const float scale_out = __uint_as_float(*amax_y_bits) * (1.0f / 127.0f);
    const float r_out = 1.0f / scale_out;
    const float2 st = row_stats[row];
    const float mu = st.x, inv = st.y;
    const int* xr = xi8 + (size_t)row * (NC / 4);
    float4* outr = (float4*)(out + (size_t)row * NC);
    const float4* g4 = (const float4*)gamma;
    const float4* b4 = (const float4*)beta;
    #pragma unroll
    for (int k = 0; k < 4; ++k) {
        int pk = xr[threadIdx.x + k * 256];
        float4 g = g4[threadIdx.x + k * 256];
        float4 b = b4[threadIdx.x + k * 256];
        float4 o;
        const float* pg = (const float*)&g;
        const float* pb = (const float*)&b;
        float* po = (float*)&o;
        #pragma unroll
        for (int j = 0; j < 4; ++j) {
            int ii = (pk << (24 - 8 * j)) >> 24;
            float q = (float)ii * scale_in;
            float y = (q - mu) * inv * pg[j] + pb[j];
            float yi = fminf(fmaxf(rintf(y * r_out), -127.f), 127.f);
            po[j] = yi * scale_out;
        }
        outr[threadIdx.x + k * 256] = o;
    }
}

extern "C" void kernel_launch(void* const* d_in, const int* in_sizes, int n_in,
                              void* d_out, int out_size, void* d_ws, size_t ws_size,
                              hipStream_t stream) {
    const float* x     = (const float*)d_in[0];
    const float* gamma = (const float*)d_in[1];
    const float* beta  = (const float*)d_in[2];
    float* out = (float*)d_out;

    const int n    = in_sizes[0];
    const int rows = n / NC;
    const int n4   = n / 4;

    // ws layout: partA[MAXBLK] | partY[MAXBLK] | row_stats[rows] | xi8[n bytes]
    float*  partA = (float*)d_ws;
    float*  partY = partA + MAXBLK;
    float2* row_stats = (float2*)((char*)d_ws + 2 * MAXBLK * sizeof(float));
    size_t i8_off = (2 * MAXBLK * sizeof(float) + (size_t)rows * 8 + 255) & ~(size_t)255;
    int* xi8 = (int*)((char*)d_ws + i8_off);
    bool ws_ok = (ws_size >= i8_off + (size_t)n);

    int occ = 0;
    hipError_t e = hipOccupancyMaxActiveBlocksPerMultiprocessor(&occ, k_fused, NTHR, 0);
    int nblk = 0;
    if (e == hipSuccess && occ > 0) nblk = min(MAXBLK, occ * 256);

    bool launched = false;
    if (ws_ok && nblk >= 256) {
        int rows_v = rows, n4_v = n4;
        void* args[] = {(void*)&x, (void*)&gamma, (void*)&beta, (void*)&out,
                        (void*)&partA, (void*)&partY, (void*)&row_stats, (void*)&xi8,
                        (void*)&rows_v, (void*)&n4_v};
        hipError_t le = hipLaunchCooperativeKernel((const void*)k_fused, dim3(nblk),
                                                   dim3(NTHR), args, 0, stream);
        launched = (le == hipSuccess);
    }

    if (!launched) {
        // fallback: 3-kernel path with same-address atomics
        unsigned int* amax_x = (unsigned int*)d_ws;
        unsigned int* amax_y = amax_x + 1;
        float2* rs2 = (float2*)((char*)d_ws + 1024);
        size_t off2 = (1024 + (size_t)rows * 8 + 255) & ~(size_t)255;
        int* xi8b = (int*)((char*)d_ws + off2);
        hipMemsetAsync(d_ws, 0, 1024, stream);
        k_absmax<<<2048, 256, 0, stream>>>(x, amax_x, n4);
        k_rowstats<<<rows, 256, 0, stream>>>(x, gamma, beta, amax_x, amax_y, rs2, xi8b);
        k_finalize_i8<<<rows, 256, 0, stream>>>(xi8b, gamma, beta, amax_x, amax_y, rs2, out);
    }
}